// Round 5
// baseline (245.722 us; speedup 1.0000x reference)
//
#include <hip/hip_runtime.h>
#include <hip/hip_bf16.h>

#define BB 8
#define NN 2048
#define CC 128
#define FF 128
#define ALPHA 0.2f
#define ROWS 16        // rows per k_out block
#define WTPAD 136      // padded LDS row stride in ushorts (272 B = 17*16B: 2-way bank alias only)
#define CHN 256        // chunks per batch
#define CLEN 8         // NN/CHN
#define CSH 3          // log2(CLEN)

typedef __hip_bfloat16 bf16;
typedef __attribute__((ext_vector_type(8))) short short8;   // 8 bf16 MFMA operand
typedef __attribute__((ext_vector_type(4))) float f32x4;    // MFMA accumulator

// ---------------- dtype helpers ----------------
__device__ __forceinline__ float ld1(const void* p, int i, int f32) {
    if (f32) return ((const float*)p)[i];
    return __bfloat162float(((const bf16*)p)[i]);
}

// Inline dtype probe: identical semantics to the old k_prep (1024 ushort2 samples,
// fp32 low-half words decode as huge bf16 values; >=64 hits -> fp32). THREADS is
// the block size; every block recomputes the (deterministic) flag locally, which
// removes the k_prep kernel and the dependent flag load at each consumer.
template <int THREADS>
__device__ __forceinline__ int probe_f32(const void* text, int* cntLds, int t) {
    if (t == 0) *cntLds = 0;
    __syncthreads();
    const ushort2* p = (const ushort2*)text;
    int local = 0;
    for (int i = t; i < 1024; i += THREADS) {
        ushort2 v = p[i];
        float f = __uint_as_float(((unsigned)v.x) << 16);
        if (!(fabsf(f) <= 100.f)) local++;
    }
    atomicAdd(cntLds, local);
    __syncthreads();
    return (*cntLds >= 64) ? 1 : 0;
}

// ---------------- K_ew: (wa in-block) + e1/e2/key for 32 rows; 8 tail blocks: WT --
// Blocks 0..511: compute wa1/wa2 redundantly (65 KB L2-hot read), then e1/e2/ukey
// for 32 rows (2 rows per wave, 8B/lane bf16 / 16B/lane fp32 vector loads).
// Blocks 512..519: WT[f*CC+cc] = bf16(W[cc*FF+f]) (the old k_prep W-transpose).
__global__ __launch_bounds__(1024) void k_ew(const void* __restrict__ text,
                                             const void* __restrict__ W,
                                             const void* __restrict__ a,
                                             float* __restrict__ e1,
                                             float* __restrict__ e2,
                                             unsigned* __restrict__ ukey,
                                             ushort* __restrict__ WT) {
    __shared__ int cnt;
    __shared__ float aL[2 * FF];
    __shared__ float wa1L[CC], wa2L[CC];
    const int t = threadIdx.x;
    const int f32 = probe_f32<1024>(text, &cnt, t);

    if (blockIdx.x >= 512) {               // ---- WT build (8 blocks) ----
        const int base = (blockIdx.x - 512) * 2048;
#pragma unroll
        for (int i = 0; i < 2; ++i) {
            int idx = base + i * 1024 + t;         // idx = cc*FF + f
            int cc = idx >> 7, f = idx & 127;
            float v = ld1(W, idx, f32);
            bf16 b = __float2bfloat16(v);
            WT[f * CC + cc] = *(const ushort*)&b;
        }
        return;
    }

    // ---- wa1/wa2 (same arithmetic/order as old k_prep) ----
    if (t < 2 * FF) aL[t] = ld1(a, t, f32);
    __syncthreads();
    if (t < CC) {
        float s1 = 0.f, s2 = 0.f;
        for (int f = 0; f < FF; f += 4) {
            float w0 = ld1(W, t * FF + f, f32);
            float w1 = ld1(W, t * FF + f + 1, f32);
            float w2 = ld1(W, t * FF + f + 2, f32);
            float w3 = ld1(W, t * FF + f + 3, f32);
            s1 += w0 * aL[f] + w1 * aL[f + 1] + w2 * aL[f + 2] + w3 * aL[f + 3];
            s2 += w0 * aL[FF + f] + w1 * aL[FF + f + 1] + w2 * aL[FF + f + 2] + w3 * aL[FF + f + 3];
        }
        wa1L[t] = s1; wa2L[t] = s2;
    }
    __syncthreads();

    // ---- e1/e2/key: wave wv handles rows blk*32 + 2wv + {0,1} (half-wave each) ----
    const int wv = t >> 6;
    const int lane = t & 63;
    const int h = lane >> 5;               // row within wave-pair
    const int l = lane & 31;               // 32 lanes per row, 4 channels each
    const int r = blockIdx.x * 32 + wv * 2 + h;
    const int c0 = 4 * l;
    float s1, s2;
    if (f32) {
        float4 q = ((const float4*)text)[r * 32 + l];
        s1 = q.x * wa1L[c0] + q.y * wa1L[c0 + 1] + q.z * wa1L[c0 + 2] + q.w * wa1L[c0 + 3];
        s2 = q.x * wa2L[c0] + q.y * wa2L[c0 + 1] + q.z * wa2L[c0 + 2] + q.w * wa2L[c0 + 3];
    } else {
        uint2 q = ((const uint2*)text)[r * 32 + l];
        float v0 = __uint_as_float((q.x & 0xFFFFu) << 16);
        float v1 = __uint_as_float(q.x & 0xFFFF0000u);
        float v2 = __uint_as_float((q.y & 0xFFFFu) << 16);
        float v3 = __uint_as_float(q.y & 0xFFFF0000u);
        s1 = v0 * wa1L[c0] + v1 * wa1L[c0 + 1] + v2 * wa1L[c0 + 2] + v3 * wa1L[c0 + 3];
        s2 = v0 * wa2L[c0] + v1 * wa2L[c0 + 1] + v2 * wa2L[c0 + 2] + v3 * wa2L[c0 + 3];
    }
#pragma unroll
    for (int m = 1; m <= 16; m <<= 1) {    // masks <32: reduce within each 32-lane half
        s1 += __shfl_xor(s1, m, 64);
        s2 += __shfl_xor(s2, m, 64);
    }
    if (l == 0) {
        e1[r] = s1; e2[r] = s2;
        unsigned m = __float_as_uint(s2);
        m = (m & 0x80000000u) ? ~m : (m | 0x80000000u);
        ukey[r] = (m & 0xFFFFF800u) | (unsigned)(r & (NN - 1));
    }
}

// ---------------- K_rank: sorted position + threshold rank by direct counting ----
__global__ __launch_bounds__(256) void k_rank(const unsigned* __restrict__ ukey,
                                              const float* __restrict__ e1,
                                              const float* __restrict__ e2,
                                              float* __restrict__ e2s,
                                              int* __restrict__ sidx,
                                              int* __restrict__ lor) {
    __shared__ unsigned kL[NN];            // 8 KB
    const int b = blockIdx.x >> 5;         // 32 blocks per batch
    const int seg = blockIdx.x & 31;
    const int t = threadIdx.x;
    {
        const uint4* src = (const uint4*)(ukey + b * NN);
        ((uint4*)kL)[t] = src[t];
        ((uint4*)kL)[256 + t] = src[256 + t];
    }
    __syncthreads();
    const int lane = t & 63;
    const int wv = t >> 6;
    const int rl = wv * 16 + (lane >> 2);  // 0..63: row within block
    const int quarter = lane & 3;          // 4 lanes share a row
    const int r = seg * 64 + rl;
    const unsigned my = kL[r];
    const float ev = e1[b * NN + r];
    unsigned mt = __float_as_uint(-ev);
    mt = (mt & 0x80000000u) ? ~mt : (mt | 0x80000000u);
    const unsigned tk = mt | 0x7FFu;       // include full idx range at threshold
    int rank = 0, lo = 0;
    const uint4* q4 = (const uint4*)&kL[quarter * 512];
#pragma unroll 4
    for (int j = 0; j < 128; ++j) {
        uint4 q = q4[j];
        rank += (q.x < my) + (q.y < my) + (q.z < my) + (q.w < my);
        lo   += (q.x <= tk) + (q.y <= tk) + (q.z <= tk) + (q.w <= tk);
    }
    rank += __shfl_xor(rank, 1, 64); lo += __shfl_xor(lo, 1, 64);
    rank += __shfl_xor(rank, 2, 64); lo += __shfl_xor(lo, 2, 64);
    if (quarter == 0) {
        e2s[b * NN + rank] = e2[b * NN + r];
        sidx[b * NN + rank] = r;
        lor[b * NN + r] = lo;
    }
}

// ---------------- K_totZ: chunk totals (blocks 0..1023) + scanZ/rig (1024..1031) --
// Both halves depend only on rank output, so they fuse into one dispatch.
__global__ __launch_bounds__(256) void k_totZ(const void* __restrict__ text,
                                              const float* __restrict__ e2s,
                                              const int* __restrict__ sidx,
                                              const float* __restrict__ e1,
                                              const int* __restrict__ lor,
                                              float* __restrict__ T1,
                                              float* __restrict__ T2,
                                              float* __restrict__ rig) {
    __shared__ int cnt;
    __shared__ float Z1L[NN + 1];          // 8.2 KB
    __shared__ float Z2L[NN + 1];          // 8.2 KB
    __shared__ float2 wtL[4];
    const int t = threadIdx.x;

    if (blockIdx.x < 1024) {
        // ---- tot: 2 chunks per block ----
        const int f32 = probe_f32<256>(text, &cnt, t);
        const int gch = blockIdx.x * 2 + (t >> 7);
        const int b = gch >> 8, ch = gch & (CHN - 1);
        const int c = t & 127;
        float r1 = 0.f, r2 = 0.f;
        const int k0 = ch * CLEN;
#pragma unroll
        for (int kk = 0; kk < CLEN; ++kk) {
            int k = k0 + kk;
            float v = e2s[b * NN + k];
            int j = sidx[b * NN + k];
            float x = ld1(text, (b * NN + j) * CC + c, f32);
            r1 += expf(v) * x;
            r2 += expf(ALPHA * v) * x;
        }
        T1[(b * (CHN + 1) + ch) * CC + c] = r1;
        T2[(b * (CHN + 1) + ch) * CC + c] = r2;
        return;
    }

    // ---- scanZ + rig for batch b: 256 threads x 8 elements ----
    const int b = blockIdx.x - 1024;
    float xa[8], xb[8], ca[8], cb[8];
    float pa = 0.f, pb = 0.f;
#pragma unroll
    for (int i = 0; i < 8; ++i) {
        float v = e2s[b * NN + 8 * t + i];
        xa[i] = expf(v); xb[i] = expf(ALPHA * v);
        pa += xa[i]; ca[i] = pa;
        pb += xb[i]; cb[i] = pb;
    }
    float sa = pa, sb = pb;
    const int lane = t & 63, wid = t >> 6;
#pragma unroll
    for (int off = 1; off < 64; off <<= 1) {
        float ya = __shfl_up(sa, off, 64);
        float yb = __shfl_up(sb, off, 64);
        if (lane >= off) { sa += ya; sb += yb; }
    }
    if (lane == 63) wtL[wid] = make_float2(sa, sb);
    __syncthreads();
    float oa = 0.f, ob = 0.f;
#pragma unroll
    for (int w2 = 0; w2 < 4; ++w2)
        if (w2 < wid) { oa += wtL[w2].x; ob += wtL[w2].y; }
    const float base_a = oa + sa - pa, base_b = ob + sb - pb;
    if (t == 0) { Z1L[0] = 0.f; Z2L[0] = 0.f; }
#pragma unroll
    for (int i = 0; i < 8; ++i) {
        Z1L[8 * t + 1 + i] = base_a + ca[i];
        Z2L[8 * t + 1 + i] = base_b + cb[i];
    }
    __syncthreads();
    const float ZN = Z1L[NN];
#pragma unroll
    for (int i = 0; i < 8; ++i) {
        const int r = 8 * t + i;
        float ev = e1[b * NN + r];
        float w1 = expf(ev), w2 = expf(ALPHA * ev);
        const int lo = lor[b * NN + r];
        float den = w1 * (ZN - Z1L[lo]) + w2 * Z2L[lo];
        den = fmaxf(den, 1e-30f);
        ((float4*)rig)[b * NN + r] = make_float4(__int_as_float(lo), w1, w2, 1.f / den);
    }
}

// ---------------- K_scan2: parallel exclusive scan of chunk totals ---------------
__global__ __launch_bounds__(256) void k_scan2(float* __restrict__ T1,
                                               float* __restrict__ T2) {
    __shared__ float2 wt[4];
    const int b = blockIdx.x >> 7, c = blockIdx.x & 127;
    const int ch = threadIdx.x;            // 0..255 == CHN
    float* P1 = T1 + (size_t)(b * (CHN + 1)) * CC + c;
    float* P2 = T2 + (size_t)(b * (CHN + 1)) * CC + c;
    const float t1 = P1[ch * CC];
    const float t2 = P2[ch * CC];
    float s1 = t1, s2 = t2;
    const int lane = ch & 63, wid = ch >> 6;
#pragma unroll
    for (int off = 1; off < 64; off <<= 1) {
        float y1 = __shfl_up(s1, off, 64);
        float y2 = __shfl_up(s2, off, 64);
        if (lane >= off) { s1 += y1; s2 += y2; }
    }
    if (lane == 63) wt[wid] = make_float2(s1, s2);
    __syncthreads();
    float o1 = 0.f, o2 = 0.f;
#pragma unroll
    for (int w2 = 0; w2 < 4; ++w2)
        if (w2 < wid) { o1 += wt[w2].x; o2 += wt[w2].y; }
    P1[ch * CC] = o1 + s1 - t1;            // exclusive base, in place
    P2[ch * CC] = o2 + s2 - t2;
    if (ch == CHN - 1) { P1[CHN * CC] = o1 + s1; P2[CHN * CC] = o2 + s2; }
}

// ---------------- K_out: ri load + residual on the fly + MFMA @W + elu -----------
__global__ __launch_bounds__(256) void k_out(const void* __restrict__ text,
                                             const ushort* __restrict__ WT,
                                             const float* __restrict__ T1,
                                             const float* __restrict__ T2,
                                             const float* __restrict__ e2s,
                                             const int* __restrict__ sidx,
                                             const float* __restrict__ rig,
                                             void* __restrict__ out) {
    __shared__ int cnt;
    __shared__ ushort WTl[FF * WTPAD];     // 34816 B, bf16 W^T padded
    __shared__ ushort ul[ROWS * WTPAD];    // 4352 B, bf16 u-tile padded
    __shared__ float4 ri[ROWS];
    const int t = threadIdx.x;
    const int f32 = probe_f32<256>(text, &cnt, t);
    const int b = blockIdx.x / (NN / ROWS);
    const int r0 = (blockIdx.x % (NN / ROWS)) * ROWS;

    // stage W^T: 2048 uint4 coalesced (L2-resident, 32 KB unique)
    {
        const uint4* src = (const uint4*)WT;
#pragma unroll
        for (int i = 0; i < 8; ++i) {
            int idx = i * 256 + t;
            uint4 v = src[idx];
            int f = idx >> 4, cb = idx & 15;
            *(uint4*)&WTl[f * WTPAD + cb * 8] = v;
        }
    }
    // per-row info precomputed in k_totZ: one coalesced float4 load
    if (t < ROWS) ri[t] = ((const float4*)rig)[b * NN + r0 + t];
    __syncthreads();

    // phase 1: u[rr][c] = (w1*(S1-P1) + w2*P2)*inv + alpha*text  -> bf16 in LDS
    {
        const int c = t & 127;
        const int g = t >> 7;                 // 0..1 -> rows g*8..g*8+7
        const float* CB1 = T1 + (size_t)(b * (CHN + 1)) * CC + c;
        const float* CB2 = T2 + (size_t)(b * (CHN + 1)) * CC + c;
        const float* e2sb = e2s + b * NN;
        const int* sxb = sidx + b * NN;
        const float S1 = CB1[CHN * CC];
#pragma unroll
        for (int q = 0; q < 8; ++q) {
            const int rr = g * 8 + q;
            float4 info = ri[rr];
            const int k = __builtin_amdgcn_readfirstlane(__float_as_int(info.x));
            const int c0 = k >> CSH;          // k==NN -> c0==CHN (total slot), cnt==0
            float P1 = CB1[c0 * CC];
            float P2 = CB2[c0 * CC];
            const int j0 = c0 * CLEN;
            const int rcnt = k - j0;          // 0..7, wave-uniform
            if (rcnt > 0) {
                float vv[CLEN - 1]; int jj[CLEN - 1];
#pragma unroll
                for (int i = 0; i < CLEN - 1; ++i) {   // j0+6 <= 2046 when rcnt>0
                    vv[i] = e2sb[j0 + i];
                    jj[i] = sxb[j0 + i];
                }
#pragma unroll
                for (int i = 0; i < CLEN - 1; ++i) {
                    if (i < rcnt) {
                        float x = ld1(text, (b * NN + jj[i]) * CC + c, f32);
                        P1 += expf(vv[i]) * x;
                        P2 += expf(ALPHA * vv[i]) * x;
                    }
                }
            }
            float tc = ld1(text, (b * NN + r0 + rr) * CC + c, f32);
            float u = (info.y * (S1 - P1) + info.z * P2) * info.w + ALPHA * tc;
            bf16 ub = __float2bfloat16(u);
            ul[rr * WTPAD + c] = *(const ushort*)&ub;
        }
    }
    __syncthreads();

    // phase 2: out[16 x 128] = elu(u @ W) via MFMA 16x16x32 bf16
    {
        const int wv = t >> 6;
        const int lane = t & 63;
        const int m = lane & 15;
        const int quad = lane >> 4;
        f32x4 acc0 = {0.f, 0.f, 0.f, 0.f};
        f32x4 acc1 = {0.f, 0.f, 0.f, 0.f};
        const int f0 = (wv * 2 + 0) * 16 + m;
        const int f1 = (wv * 2 + 1) * 16 + m;
#pragma unroll
        for (int kt = 0; kt < 4; ++kt) {
            const int ko = kt * 32 + quad * 8;
            short8 afrag = *(const short8*)&ul[m * WTPAD + ko];
            short8 bf0 = *(const short8*)&WTl[f0 * WTPAD + ko];
            short8 bf1 = *(const short8*)&WTl[f1 * WTPAD + ko];
            acc0 = __builtin_amdgcn_mfma_f32_16x16x32_bf16(afrag, bf0, acc0, 0, 0, 0);
            acc1 = __builtin_amdgcn_mfma_f32_16x16x32_bf16(afrag, bf1, acc1, 0, 0, 0);
        }
        // C/D: col = lane&15 (f within tile), row = quad*4+reg (u-row)
#pragma unroll
        for (int ft = 0; ft < 2; ++ft) {
            f32x4 acc = ft ? acc1 : acc0;
            const int f = (wv * 2 + ft) * 16 + m;
#pragma unroll
            for (int reg = 0; reg < 4; ++reg) {
                const int urow = quad * 4 + reg;
                float x = acc[reg];
                float y = x > 0.f ? x : expm1f(x);
                const int orow = b * NN + r0 + urow;
                if (f32) ((float*)out)[orow * FF + f] = y;
                else     ((bf16*)out)[orow * FF + f] = __float2bfloat16(y);
            }
        }
    }
}

extern "C" void kernel_launch(void* const* d_in, const int* in_sizes, int n_in,
                              void* d_out, int out_size, void* d_ws, size_t ws_size,
                              hipStream_t stream) {
    const void* text = d_in[0];
    const void* Wp   = (n_in >= 4) ? d_in[2] : d_in[1];
    const void* ap   = (n_in >= 4) ? d_in[3] : d_in[2];
    for (int i = 0; i < n_in; ++i) {
        int s = in_sizes[i];
        if (s == BB * NN * CC)      text = d_in[i];
        else if (s == CC * FF)      Wp = d_in[i];
        else if (s == 2 * FF)       ap = d_in[i];
    }

    float* w = (float*)d_ws;
    size_t off = 0;
    ushort*   WT    = (ushort*)(w + off);   off += 8192;           // 16K bf16
    float*    e1    = w + off;              off += BB * NN;
    float*    e2    = w + off;              off += BB * NN;
    unsigned* ukey  = (unsigned*)(w + off); off += BB * NN;
    float*    e2s   = w + off;              off += BB * NN;
    int*      sidx  = (int*)(w + off);      off += BB * NN;
    int*      lor   = (int*)(w + off);      off += BB * NN;
    float*    rig   = w + off;              off += (size_t)4 * BB * NN;  // float4/row
    float*    T1    = w + off;              off += (size_t)BB * (CHN + 1) * CC;
    float*    T2    = w + off;              off += (size_t)BB * (CHN + 1) * CC;

    k_ew<<<520, 1024, 0, stream>>>(text, Wp, ap, e1, e2, ukey, WT);
    k_rank<<<BB * 32, 256, 0, stream>>>(ukey, e1, e2, e2s, sidx, lor);
    k_totZ<<<1032, 256, 0, stream>>>(text, e2s, sidx, e1, lor, T1, T2, rig);
    k_scan2<<<BB * CC, 256, 0, stream>>>(T1, T2);
    k_out<<<BB * NN / ROWS, 256, 0, stream>>>(text, WT, T1, T2, e2s, sidx,
                                              rig, d_out);
}